// Round 1
// baseline (575.237 us; speedup 1.0000x reference)
//
#include <hip/hip_runtime.h>
#include <cstdint>
#include <cstddef>

// PositionalEncoderGrid: Instant-NGP style multiresolution hash grid encoding.
// B=524288 points, L=16 levels, T=2^19 table entries/level, F=2 features.
// One thread per (point, level); gid = b*16 + l so the float2 output store is
// fully coalesced. 8 corner gathers of float2 per thread.

#define NUM_LEVELS 16
#define TBL_SIZE (1u << 19)
#define TBL_MASK (TBL_SIZE - 1u)
#define PRIME_Y 2654435761u
#define PRIME_Z 805459861u

// N_l = int(16 * (2^(1/3))^l), matching the host-side math.exp construction.
__constant__ float c_ns[NUM_LEVELS] = {
    16.f, 20.f, 25.f, 32.f, 40.f, 50.f, 64.f, 80.f,
    101.f, 128.f, 161.f, 203.f, 256.f, 322.f, 406.f, 512.f
};

__global__ __launch_bounds__(256) void hashgrid_enc_kernel(
    const float* __restrict__ in,      // [B,3]
    const float* __restrict__ table,   // [L,T,2]
    float2* __restrict__ out)          // [B,16] float2
{
    const int gid = blockIdx.x * 256 + threadIdx.x;
    const int b = gid >> 4;
    const int l = gid & 15;

    // 16 lanes share one point: same-address loads broadcast from L1.
    const float vx = in[b * 3 + 0];
    const float vy = in[b * 3 + 1];
    const float vz = in[b * 3 + 2];

    // x = (v + BOUND) / (2*BOUND), fp32 like the reference.
    const float xs = (vx + 3.0f) / 6.0f;
    const float ys = (vy + 3.0f) / 6.0f;
    const float zs = (vz + 3.0f) / 6.0f;

    const float n = c_ns[l];
    const float tx = xs * n;
    const float ty = ys * n;
    const float tz = zs * n;

    const float fpx = floorf(tx);
    const float fpy = floorf(ty);
    const float fpz = floorf(tz);

    // Fractional position in cell; consistent with the floor above, so the
    // interpolation is continuous even where we differ from the reference by
    // an ulp at a cell boundary.
    const float fx = tx - fpx;
    const float fy = ty - fpy;
    const float fz = tz - fpz;

    const uint32_t px = (uint32_t)fpx;
    const uint32_t py = (uint32_t)fpy;
    const uint32_t pz = (uint32_t)fpz;

    const uint32_t hx0 = px;                 // prime_x = 1
    const uint32_t hx1 = px + 1u;
    const uint32_t hy0 = py * PRIME_Y;
    const uint32_t hy1 = hy0 + PRIME_Y;      // (py+1)*P mod 2^32
    const uint32_t hz0 = pz * PRIME_Z;
    const uint32_t hz1 = hz0 + PRIME_Z;

    const float2* __restrict__ tb = ((const float2*)table) + ((size_t)l << 19);

    const uint32_t i000 = (hx0 ^ hy0 ^ hz0) & TBL_MASK;
    const uint32_t i001 = (hx0 ^ hy0 ^ hz1) & TBL_MASK;
    const uint32_t i010 = (hx0 ^ hy1 ^ hz0) & TBL_MASK;
    const uint32_t i011 = (hx0 ^ hy1 ^ hz1) & TBL_MASK;
    const uint32_t i100 = (hx1 ^ hy0 ^ hz0) & TBL_MASK;
    const uint32_t i101 = (hx1 ^ hy0 ^ hz1) & TBL_MASK;
    const uint32_t i110 = (hx1 ^ hy1 ^ hz0) & TBL_MASK;
    const uint32_t i111 = (hx1 ^ hy1 ^ hz1) & TBL_MASK;

    // Issue all 8 gathers before any use (ILP to hide L2/L3 latency).
    const float2 f000 = tb[i000];
    const float2 f001 = tb[i001];
    const float2 f010 = tb[i010];
    const float2 f011 = tb[i011];
    const float2 f100 = tb[i100];
    const float2 f101 = tb[i101];
    const float2 f110 = tb[i110];
    const float2 f111 = tb[i111];

    const float wx1 = fx, wx0 = 1.0f - fx;
    const float wy1 = fy, wy0 = 1.0f - fy;
    const float wz1 = fz, wz0 = 1.0f - fz;

    float a0 = 0.0f, a1 = 0.0f;
    float w;
    w = wx0 * wy0 * wz0; a0 = fmaf(f000.x, w, a0); a1 = fmaf(f000.y, w, a1);
    w = wx0 * wy0 * wz1; a0 = fmaf(f001.x, w, a0); a1 = fmaf(f001.y, w, a1);
    w = wx0 * wy1 * wz0; a0 = fmaf(f010.x, w, a0); a1 = fmaf(f010.y, w, a1);
    w = wx0 * wy1 * wz1; a0 = fmaf(f011.x, w, a0); a1 = fmaf(f011.y, w, a1);
    w = wx1 * wy0 * wz0; a0 = fmaf(f100.x, w, a0); a1 = fmaf(f100.y, w, a1);
    w = wx1 * wy0 * wz1; a0 = fmaf(f101.x, w, a0); a1 = fmaf(f101.y, w, a1);
    w = wx1 * wy1 * wz0; a0 = fmaf(f110.x, w, a0); a1 = fmaf(f110.y, w, a1);
    w = wx1 * wy1 * wz1; a0 = fmaf(f111.x, w, a0); a1 = fmaf(f111.y, w, a1);

    out[gid] = make_float2(a0, a1);
}

extern "C" void kernel_launch(void* const* d_in, const int* in_sizes, int n_in,
                              void* d_out, int out_size, void* d_ws, size_t ws_size,
                              hipStream_t stream) {
    const float* inputs = (const float*)d_in[0];   // [B,3] fp32
    const float* table  = (const float*)d_in[1];   // [16, 2^19, 2] fp32
    float2* out = (float2*)d_out;                  // [B, 16] float2

    const int B = in_sizes[0] / 3;                 // 524288
    const int total = B * NUM_LEVELS;              // 8388608 threads
    const int blocks = total / 256;                // 32768

    hashgrid_enc_kernel<<<blocks, 256, 0, stream>>>(inputs, table, out);
}

// Round 2
// 448.099 us; speedup vs baseline: 1.2837x; 1.2837x over previous
//
#include <hip/hip_runtime.h>
#include <cstdint>
#include <cstddef>

// PositionalEncoderGrid: Instant-NGP multiresolution hash grid.
// B=524288 points, L=16 levels, T=2^19 entries/level, F=2 floats.
//
// R1 strategy: level-partitioned blocks for per-XCD L2 table locality.
//   Phase A: grid of 16 level-slots x 2048 point-chunks; slot v=blockIdx%16
//            -> XCD v%8 (empirical round-robin). level = v<8 ? 15-v : v-8
//            pairs one fine level (~4MB working set) with one coarse level
//            per XCD, so each XCD's 4MB L2 holds its tables resident.
//            Writes level-major ws[l*B+p] fully coalesced.
//   Phase B: transpose ws[l*B+p] -> out[p*16+l]; coalesced reads, each wave
//            fully covers its 128B output lines (no cross-XCD partial lines).
// Fallback (ws too small): phase A writes out[p*16+l] directly (scattered).

#define NUM_LEVELS 16
#define TBL_MASK ((1u << 19) - 1u)
#define PRIME_Y 2654435761u
#define PRIME_Z 805459861u
#define BATCH 524288

__constant__ float c_ns[NUM_LEVELS] = {
    16.f, 20.f, 25.f, 32.f, 40.f, 50.f, 64.f, 80.f,
    101.f, 128.f, 161.f, 203.f, 256.f, 322.f, 406.f, 512.f
};

__device__ __forceinline__ float2 encode_one(
    const float* __restrict__ in, const float* __restrict__ table,
    int p, int l)
{
    const float vx = in[p * 3 + 0];
    const float vy = in[p * 3 + 1];
    const float vz = in[p * 3 + 2];

    const float xs = (vx + 3.0f) / 6.0f;
    const float ys = (vy + 3.0f) / 6.0f;
    const float zs = (vz + 3.0f) / 6.0f;

    const float n = c_ns[l];
    const float tx = xs * n, ty = ys * n, tz = zs * n;
    const float fpx = floorf(tx), fpy = floorf(ty), fpz = floorf(tz);
    const float fx = tx - fpx, fy = ty - fpy, fz = tz - fpz;

    const uint32_t px = (uint32_t)fpx;
    const uint32_t py = (uint32_t)fpy;
    const uint32_t pz = (uint32_t)fpz;

    const uint32_t hx0 = px;
    const uint32_t hx1 = px + 1u;
    const uint32_t hy0 = py * PRIME_Y;
    const uint32_t hy1 = hy0 + PRIME_Y;
    const uint32_t hz0 = pz * PRIME_Z;
    const uint32_t hz1 = hz0 + PRIME_Z;

    const float2* __restrict__ tb = ((const float2*)table) + ((size_t)l << 19);

    const uint32_t i000 = (hx0 ^ hy0 ^ hz0) & TBL_MASK;
    const uint32_t i001 = (hx0 ^ hy0 ^ hz1) & TBL_MASK;
    const uint32_t i010 = (hx0 ^ hy1 ^ hz0) & TBL_MASK;
    const uint32_t i011 = (hx0 ^ hy1 ^ hz1) & TBL_MASK;
    const uint32_t i100 = (hx1 ^ hy0 ^ hz0) & TBL_MASK;
    const uint32_t i101 = (hx1 ^ hy0 ^ hz1) & TBL_MASK;
    const uint32_t i110 = (hx1 ^ hy1 ^ hz0) & TBL_MASK;
    const uint32_t i111 = (hx1 ^ hy1 ^ hz1) & TBL_MASK;

    const float2 f000 = tb[i000];
    const float2 f001 = tb[i001];
    const float2 f010 = tb[i010];
    const float2 f011 = tb[i011];
    const float2 f100 = tb[i100];
    const float2 f101 = tb[i101];
    const float2 f110 = tb[i110];
    const float2 f111 = tb[i111];

    const float wx1 = fx, wx0 = 1.0f - fx;
    const float wy1 = fy, wy0 = 1.0f - fy;
    const float wz1 = fz, wz0 = 1.0f - fz;

    float a0 = 0.0f, a1 = 0.0f, w;
    w = wx0 * wy0 * wz0; a0 = fmaf(f000.x, w, a0); a1 = fmaf(f000.y, w, a1);
    w = wx0 * wy0 * wz1; a0 = fmaf(f001.x, w, a0); a1 = fmaf(f001.y, w, a1);
    w = wx0 * wy1 * wz0; a0 = fmaf(f010.x, w, a0); a1 = fmaf(f010.y, w, a1);
    w = wx0 * wy1 * wz1; a0 = fmaf(f011.x, w, a0); a1 = fmaf(f011.y, w, a1);
    w = wx1 * wy0 * wz0; a0 = fmaf(f100.x, w, a0); a1 = fmaf(f100.y, w, a1);
    w = wx1 * wy0 * wz1; a0 = fmaf(f101.x, w, a0); a1 = fmaf(f101.y, w, a1);
    w = wx1 * wy1 * wz0; a0 = fmaf(f110.x, w, a0); a1 = fmaf(f110.y, w, a1);
    w = wx1 * wy1 * wz1; a0 = fmaf(f111.x, w, a0); a1 = fmaf(f111.y, w, a1);
    return make_float2(a0, a1);
}

// Phase A: level-major compute into ws[l*B + p].
__global__ __launch_bounds__(256) void enc_level_major_kernel(
    const float* __restrict__ in,
    const float* __restrict__ table,
    float2* __restrict__ ws)           // [L, B] float2
{
    const int v = blockIdx.x & 15;             // level slot -> XCD v%8
    const int chunk = blockIdx.x >> 4;
    const int l = (v < 8) ? (15 - v) : (v - 8); // pair fine+coarse per XCD
    const int p = chunk * 256 + threadIdx.x;

    const float2 r = encode_one(in, table, p, l);
    ws[(size_t)l * BATCH + p] = r;             // fully coalesced
}

// Phase B: transpose [L,B] -> [B,L]. One thread per point; reads are
// wave-coalesced per level; the wave's 8 float4 stores fully cover its
// 8KB output span (full-line writebacks on one XCD).
__global__ __launch_bounds__(256) void transpose_kernel(
    const float2* __restrict__ ws,     // [L, B]
    float4* __restrict__ out)          // [B, 8] float4 view of [B,16] float2
{
    const int p = blockIdx.x * 256 + threadIdx.x;

    float2 v[NUM_LEVELS];
#pragma unroll
    for (int l = 0; l < NUM_LEVELS; ++l)
        v[l] = ws[(size_t)l * BATCH + p];

#pragma unroll
    for (int j = 0; j < 8; ++j) {
        out[(size_t)p * 8 + j] =
            make_float4(v[2 * j].x, v[2 * j].y, v[2 * j + 1].x, v[2 * j + 1].y);
    }
}

// Fallback: direct scatter store (no workspace needed).
__global__ __launch_bounds__(256) void enc_scatter_kernel(
    const float* __restrict__ in,
    const float* __restrict__ table,
    float2* __restrict__ out)          // [B, 16] float2
{
    const int v = blockIdx.x & 15;
    const int chunk = blockIdx.x >> 4;
    const int l = (v < 8) ? (15 - v) : (v - 8);
    const int p = chunk * 256 + threadIdx.x;

    const float2 r = encode_one(in, table, p, l);
    out[(size_t)p * NUM_LEVELS + l] = r;
}

extern "C" void kernel_launch(void* const* d_in, const int* in_sizes, int n_in,
                              void* d_out, int out_size, void* d_ws, size_t ws_size,
                              hipStream_t stream) {
    const float* inputs = (const float*)d_in[0];   // [B,3] fp32
    const float* table  = (const float*)d_in[1];   // [16, 2^19, 2] fp32

    const size_t ws_needed = (size_t)NUM_LEVELS * BATCH * sizeof(float2); // 64 MiB

    if (ws_size >= ws_needed) {
        float2* ws = (float2*)d_ws;
        enc_level_major_kernel<<<32768, 256, 0, stream>>>(inputs, table, ws);
        transpose_kernel<<<2048, 256, 0, stream>>>(ws, (float4*)d_out);
    } else {
        enc_scatter_kernel<<<32768, 256, 0, stream>>>(inputs, table, (float2*)d_out);
    }
}

// Round 4
// 431.198 us; speedup vs baseline: 1.3340x; 1.0392x over previous
//
#include <hip/hip_runtime.h>
#include <cstdint>
#include <cstddef>
#include <cstring>

// PositionalEncoderGrid: Instant-NGP multiresolution hash grid.
// B=524288 points, L=16 levels, T=2^19 entries/level, F=2 floats.
//
// R3: - Phase A: level-partitioned blocks (slot v=blockIdx%16 -> XCD v%8,
//       level = v<8 ? 15-v : v-8) keeps each XCD's 2 level tables L2/L3
//       resident (R1: steady-state HBM fetch ~0). 2 points/thread for
//       16 gathers in flight; nontemporal table loads on fine levels
//       (loaded as double — the builtin rejects HIP vector types).
//     - Phase B: one thread per output float4 -> perfectly coalesced 16B
//       lane writes.

#define NUM_LEVELS 16
#define TBL_MASK ((1u << 19) - 1u)
#define PRIME_Y 2654435761u
#define PRIME_Z 805459861u
#define BATCH 524288

__constant__ float c_ns[NUM_LEVELS] = {
    16.f, 20.f, 25.f, 32.f, 40.f, 50.f, 64.f, 80.f,
    101.f, 128.f, 161.f, 203.f, 256.f, 322.f, 406.f, 512.f
};

struct Corner8 {
    uint32_t i[8];
    float wx0, wy0, wz0;
};

__device__ __forceinline__ float2 d2f2(double d) {
    union { double d; float2 f; } u;
    u.d = d;
    return u.f;
}

__device__ __forceinline__ Corner8 corner_setup(
    const float* __restrict__ in, int p, float n)
{
    const float vx = in[p * 3 + 0];
    const float vy = in[p * 3 + 1];
    const float vz = in[p * 3 + 2];

    const float xs = (vx + 3.0f) / 6.0f;
    const float ys = (vy + 3.0f) / 6.0f;
    const float zs = (vz + 3.0f) / 6.0f;

    const float tx = xs * n, ty = ys * n, tz = zs * n;
    const float fpx = floorf(tx), fpy = floorf(ty), fpz = floorf(tz);

    Corner8 c;
    c.wx0 = tx - fpx;   // fractional part (weight for offset=1 axis)
    c.wy0 = ty - fpy;
    c.wz0 = tz - fpz;

    const uint32_t px = (uint32_t)fpx;
    const uint32_t py = (uint32_t)fpy;
    const uint32_t pz = (uint32_t)fpz;

    const uint32_t hx0 = px;
    const uint32_t hx1 = px + 1u;
    const uint32_t hy0 = py * PRIME_Y;
    const uint32_t hy1 = hy0 + PRIME_Y;
    const uint32_t hz0 = pz * PRIME_Z;
    const uint32_t hz1 = hz0 + PRIME_Z;

    c.i[0] = (hx0 ^ hy0 ^ hz0) & TBL_MASK;
    c.i[1] = (hx0 ^ hy0 ^ hz1) & TBL_MASK;
    c.i[2] = (hx0 ^ hy1 ^ hz0) & TBL_MASK;
    c.i[3] = (hx0 ^ hy1 ^ hz1) & TBL_MASK;
    c.i[4] = (hx1 ^ hy0 ^ hz0) & TBL_MASK;
    c.i[5] = (hx1 ^ hy0 ^ hz1) & TBL_MASK;
    c.i[6] = (hx1 ^ hy1 ^ hz0) & TBL_MASK;
    c.i[7] = (hx1 ^ hy1 ^ hz1) & TBL_MASK;
    return c;
}

__device__ __forceinline__ float2 blend(const Corner8& c, const float2 f[8])
{
    const float wx1 = c.wx0, wx0 = 1.0f - c.wx0;
    const float wy1 = c.wy0, wy0 = 1.0f - c.wy0;
    const float wz1 = c.wz0, wz0 = 1.0f - c.wz0;

    float a0 = 0.0f, a1 = 0.0f, w;
    w = wx0 * wy0 * wz0; a0 = fmaf(f[0].x, w, a0); a1 = fmaf(f[0].y, w, a1);
    w = wx0 * wy0 * wz1; a0 = fmaf(f[1].x, w, a0); a1 = fmaf(f[1].y, w, a1);
    w = wx0 * wy1 * wz0; a0 = fmaf(f[2].x, w, a0); a1 = fmaf(f[2].y, w, a1);
    w = wx0 * wy1 * wz1; a0 = fmaf(f[3].x, w, a0); a1 = fmaf(f[3].y, w, a1);
    w = wx1 * wy0 * wz0; a0 = fmaf(f[4].x, w, a0); a1 = fmaf(f[4].y, w, a1);
    w = wx1 * wy0 * wz1; a0 = fmaf(f[5].x, w, a0); a1 = fmaf(f[5].y, w, a1);
    w = wx1 * wy1 * wz0; a0 = fmaf(f[6].x, w, a0); a1 = fmaf(f[6].y, w, a1);
    w = wx1 * wy1 * wz1; a0 = fmaf(f[7].x, w, a0); a1 = fmaf(f[7].y, w, a1);
    return make_float2(a0, a1);
}

// Phase A: level-major compute into ws[l*B + p]; 2 points per thread.
__global__ __launch_bounds__(256) void enc_level_major_kernel(
    const float* __restrict__ in,
    const float* __restrict__ table,
    float2* __restrict__ ws)           // [L, B] float2
{
    const int v = blockIdx.x & 15;              // level slot -> XCD v%8
    const int chunk = blockIdx.x >> 4;          // 1024 chunks of 512 points
    const int l = (v < 8) ? (15 - v) : (v - 8); // fine+coarse paired per XCD
    const int p0 = chunk * 512 + threadIdx.x;
    const int p1 = p0 + 256;

    const float n = c_ns[l];
    const Corner8 cA = corner_setup(in, p0, n);
    const Corner8 cB = corner_setup(in, p1, n);

    const double* __restrict__ tb =
        ((const double*)table) + ((size_t)l << 19);   // 8B entries

    // Issue all 16 gathers before any use. Fine levels (>=2) use
    // nontemporal loads: their ~4MB working sets thrash L1 anyway; keep
    // L1 for the coarse-level blocks co-resident on the same CU.
    float2 fA[8], fB[8];
    if (l >= 2) {
#pragma unroll
        for (int k = 0; k < 8; ++k)
            fA[k] = d2f2(__builtin_nontemporal_load(&tb[cA.i[k]]));
#pragma unroll
        for (int k = 0; k < 8; ++k)
            fB[k] = d2f2(__builtin_nontemporal_load(&tb[cB.i[k]]));
    } else {
#pragma unroll
        for (int k = 0; k < 8; ++k) fA[k] = d2f2(tb[cA.i[k]]);
#pragma unroll
        for (int k = 0; k < 8; ++k) fB[k] = d2f2(tb[cB.i[k]]);
    }

    ws[(size_t)l * BATCH + p0] = blend(cA, fA);
    ws[(size_t)l * BATCH + p1] = blend(cB, fB);
}

// Phase B: transpose [L,B] float2 -> [B,8] float4. One thread per output
// float4: writes 16B/lane fully coalesced; reads are 8x64B segments/wave.
__global__ __launch_bounds__(256) void transpose_kernel(
    const float2* __restrict__ ws,     // [L, B]
    float4* __restrict__ out)          // [B*8]
{
    const int gid = blockIdx.x * 256 + threadIdx.x;  // 0 .. B*8-1
    const int p = gid >> 3;
    const int j = gid & 7;

    const float2 a = ws[(size_t)(2 * j) * BATCH + p];
    const float2 b = ws[(size_t)(2 * j + 1) * BATCH + p];
    out[gid] = make_float4(a.x, a.y, b.x, b.y);
}

// Fallback: direct scatter store (no workspace needed).
__global__ __launch_bounds__(256) void enc_scatter_kernel(
    const float* __restrict__ in,
    const float* __restrict__ table,
    float2* __restrict__ out)          // [B, 16] float2
{
    const int v = blockIdx.x & 15;
    const int chunk = blockIdx.x >> 4;
    const int l = (v < 8) ? (15 - v) : (v - 8);
    const int p = chunk * 256 + threadIdx.x;

    const float n = c_ns[l];
    const Corner8 c = corner_setup(in, p, n);
    const double* __restrict__ tb = ((const double*)table) + ((size_t)l << 19);
    float2 f[8];
#pragma unroll
    for (int k = 0; k < 8; ++k) f[k] = d2f2(tb[c.i[k]]);
    out[(size_t)p * NUM_LEVELS + l] = blend(c, f);
}

extern "C" void kernel_launch(void* const* d_in, const int* in_sizes, int n_in,
                              void* d_out, int out_size, void* d_ws, size_t ws_size,
                              hipStream_t stream) {
    const float* inputs = (const float*)d_in[0];   // [B,3] fp32
    const float* table  = (const float*)d_in[1];   // [16, 2^19, 2] fp32

    const size_t ws_needed = (size_t)NUM_LEVELS * BATCH * sizeof(float2); // 64 MiB

    if (ws_size >= ws_needed) {
        float2* ws = (float2*)d_ws;
        // 16 level-slots x 1024 chunks (512 points each) = 16384 blocks
        enc_level_major_kernel<<<16384, 256, 0, stream>>>(inputs, table, ws);
        // B*8 float4 outputs / 256 = 16384 blocks
        transpose_kernel<<<16384, 256, 0, stream>>>(ws, (float4*)d_out);
    } else {
        enc_scatter_kernel<<<32768, 256, 0, stream>>>(inputs, table, (float2*)d_out);
    }
}